// Round 1
// baseline (1128.519 us; speedup 1.0000x reference)
//
#include <hip/hip_runtime.h>

#define B_ 4
#define C_ 384
#define N_ 4096
#define NH_ 8
#define D_ 48
#define PK_ 64
#define J3_ 1152
#define CN_ (C_*N_)

using bf16x8 = __attribute__((ext_vector_type(8))) __bf16;
using f32x4  = __attribute__((ext_vector_type(4))) float;
using f4     = __attribute__((ext_vector_type(4))) float;

__device__ __forceinline__ float bf2f(unsigned short u){ return __uint_as_float(((unsigned)u)<<16); }
__device__ __forceinline__ unsigned short f2bf(float f){
  unsigned x = __float_as_uint(f);
  x += 0x7fffu + ((x>>16)&1u);
  return (unsigned short)(x>>16);
}

// ---- 1) x [B,C,N] f32 -> xb [B,N,C] bf16 (tiled transpose) ----
__global__ __launch_bounds__(256) void k_tx(const float* __restrict__ x, unsigned short* __restrict__ xb){
  __shared__ float tile[32][33];
  int b = blockIdx.z, n0 = blockIdx.x*32, c0 = blockIdx.y*32;
  int t = threadIdx.x, tr = t>>5, tc = t&31;
  #pragma unroll
  for(int i=0;i<4;i++)
    tile[tr+i*8][tc] = x[(size_t)b*CN_ + (size_t)(c0+tr+i*8)*N_ + n0+tc];
  __syncthreads();
  #pragma unroll
  for(int i=0;i<4;i++)
    xb[((size_t)b*N_ + n0+tr+i*8)*C_ + c0+tc] = f2bf(tile[tc][tr+i*8]);
}

// ---- 2) Wq [C,1536] f32 -> Wt [1152,384] bf16 (slices {0,1,3}, transposed) ----
__global__ __launch_bounds__(256) void k_pw(const float* __restrict__ Wq, unsigned short* __restrict__ Wt){
  __shared__ float tile[32][33];
  int j0 = blockIdx.x*32, c0 = blockIdx.y*32;
  int t = threadIdx.x, tr = t>>5, tc = t&31;
  #pragma unroll
  for(int i=0;i<4;i++){
    int c = c0+tr+i*8;
    int jp = j0+tc;
    int s = jp/384; int srcs = (s==2)?3:s;
    tile[tr+i*8][tc] = Wq[(size_t)c*1536 + srcs*384 + (jp - s*384)];
  }
  __syncthreads();
  #pragma unroll
  for(int i=0;i<4;i++){
    int j = j0+tr+i*8, c = c0+tc;
    Wt[(size_t)j*C_ + c] = f2bf(tile[tc][tr+i*8]);
  }
}

// ---- 3) qkv [16384,1152] bf16 = xb [16384,384] @ Wt^T, MFMA 16x16x32 ----
__global__ __launch_bounds__(256) void k_gemm(const unsigned short* __restrict__ A,
                                              const unsigned short* __restrict__ Bt,
                                              unsigned short* __restrict__ Cc){
  __shared__ alignas(16) unsigned short As[128*64];
  __shared__ alignas(16) unsigned short Bs[128*64];
  int t = threadIdx.x;
  int w = t>>6, l = t&63;
  int m0 = blockIdx.x*128, j0 = blockIdx.y*128;
  int lrow = l & 15;
  int rb = (w>>1)*64, cb = (w&1)*64;
  f32x4 acc[4][4] = {};
  for(int kt=0;kt<6;kt++){
    __syncthreads();
    int k0 = kt*64;
    #pragma unroll
    for(int i=0;i<4;i++){
      int r = (t>>3) + i*32;
      int slot = (t&7) ^ (r&7);          // inverse-swizzled global source (rule #21)
      const unsigned short* ga = A  + (size_t)(m0+r)*384 + k0 + slot*8;
      __builtin_amdgcn_global_load_lds((const __attribute__((address_space(1))) void*)ga,
                                       (__attribute__((address_space(3))) void*)(As + i*2048 + t*8), 16, 0, 0);
      const unsigned short* gb = Bt + (size_t)(j0+r)*384 + k0 + slot*8;
      __builtin_amdgcn_global_load_lds((const __attribute__((address_space(1))) void*)gb,
                                       (__attribute__((address_space(3))) void*)(Bs + i*2048 + t*8), 16, 0, 0);
    }
    __syncthreads();
    #pragma unroll
    for(int ks=0;ks<2;ks++){
      int kb0 = (ks*32 + ((l>>4)<<3))*2;  // byte offset of this lane's k-octet
      bf16x8 af[4], bf[4];
      #pragma unroll
      for(int mi=0;mi<4;mi++){
        int r = rb + mi*16 + lrow;
        int off = (r*128 + kb0) ^ ((r&7)<<4);   // swizzled ds_read
        af[mi] = *reinterpret_cast<const bf16x8*>((const char*)As + off);
      }
      #pragma unroll
      for(int ni=0;ni<4;ni++){
        int r = cb + ni*16 + lrow;
        int off = (r*128 + kb0) ^ ((r&7)<<4);
        bf[ni] = *reinterpret_cast<const bf16x8*>((const char*)Bs + off);
      }
      #pragma unroll
      for(int mi=0;mi<4;mi++)
        #pragma unroll
        for(int ni=0;ni<4;ni++)
          acc[mi][ni] = __builtin_amdgcn_mfma_f32_16x16x32_bf16(af[mi], bf[ni], acc[mi][ni], 0,0,0);
    }
  }
  int rq = (l>>4)<<2;
  #pragma unroll
  for(int mi=0;mi<4;mi++){
    #pragma unroll
    for(int ni=0;ni<4;ni++){
      int row = m0 + rb + mi*16 + rq;     // D: row=(l>>4)*4+q, col=l&15 (m89 verified)
      int col = j0 + cb + ni*16 + lrow;
      #pragma unroll
      for(int q=0;q<4;q++)
        Cc[(size_t)(row+q)*J3_ + col] = f2bf(acc[mi][ni][q]);
    }
  }
}

// ---- 4) scale[b][c'] = temp2[h] / max(||q_col||, 1e-12), norm over N ----
__global__ __launch_bounds__(256) void k_norm(const unsigned short* __restrict__ qkv,
                                              const float* __restrict__ temp2,
                                              float* __restrict__ scale){
  __shared__ float red[256];
  int b = blockIdx.x; int cc = blockIdx.y*64 + (threadIdx.x&63); int g = threadIdx.x>>6;
  float acc = 0.f;
  for(int n=g;n<N_;n+=4){
    float v = bf2f(qkv[((size_t)(b*N_+n))*J3_ + cc]);   // slice 0 = q
    acc += v*v;
  }
  red[threadIdx.x] = acc;
  __syncthreads();
  if(threadIdx.x < 64){
    float s = red[threadIdx.x] + red[threadIdx.x+64] + red[threadIdx.x+128] + red[threadIdx.x+192];
    int c = blockIdx.y*64 + threadIdx.x;
    float nrm = fmaxf(sqrtf(s), 1e-12f);
    scale[b*C_ + c] = temp2[c/48] / nrm;
  }
}

// ---- 5) kv[b][s][c'][kk] = sum_n qkv[b,n,slice(s+1),c'] * EF[n,kk] ----
__global__ __launch_bounds__(256) void k_kvproj(const unsigned short* __restrict__ qkv,
                                                const float* __restrict__ EF,
                                                float* __restrict__ kv){
  int b = blockIdx.x, s = blockIdx.y;
  int w = threadIdx.x>>6, lane = threadIdx.x&63;
  int c0 = (blockIdx.z*4 + w)*16;
  float acc[16];
  #pragma unroll
  for(int j=0;j<16;j++) acc[j]=0.f;
  const unsigned short* base = qkv + (size_t)b*N_*J3_ + (s+1)*384 + c0;
  for(int n=0;n<N_;n++){
    const uint4* p = reinterpret_cast<const uint4*>(base + (size_t)n*J3_);
    uint4 u0 = p[0], u1 = p[1];
    float ef = EF[n*PK_ + lane];
    float vals[16];
    vals[0]=__uint_as_float(u0.x<<16);  vals[1]=__uint_as_float(u0.x&0xffff0000u);
    vals[2]=__uint_as_float(u0.y<<16);  vals[3]=__uint_as_float(u0.y&0xffff0000u);
    vals[4]=__uint_as_float(u0.z<<16);  vals[5]=__uint_as_float(u0.z&0xffff0000u);
    vals[6]=__uint_as_float(u0.w<<16);  vals[7]=__uint_as_float(u0.w&0xffff0000u);
    vals[8]=__uint_as_float(u1.x<<16);  vals[9]=__uint_as_float(u1.x&0xffff0000u);
    vals[10]=__uint_as_float(u1.y<<16); vals[11]=__uint_as_float(u1.y&0xffff0000u);
    vals[12]=__uint_as_float(u1.z<<16); vals[13]=__uint_as_float(u1.z&0xffff0000u);
    vals[14]=__uint_as_float(u1.w<<16); vals[15]=__uint_as_float(u1.w&0xffff0000u);
    #pragma unroll
    for(int j=0;j<16;j++) acc[j] = fmaf(vals[j], ef, acc[j]);
  }
  #pragma unroll
  for(int j=0;j<16;j++)
    kv[(((size_t)b*2 + s)*384 + c0 + j)*PK_ + lane] = acc[j];
}

// ---- 6) fused attention: logits -> softmax(64) -> PV; writes xsa[b][(dd*8+hh)*N + n] ----
__global__ __launch_bounds__(256) void k_attn(const unsigned short* __restrict__ qkv,
                                              const float* __restrict__ scale,
                                              const float* __restrict__ kv,
                                              float* __restrict__ xsa){
  __shared__ float qs[64*52];   // q*scale, later reused as output tile
  __shared__ float kp[64*52];   // [kk][dd] padded
  __shared__ float vp[48*68];   // [dd][kk] padded
  __shared__ float pbuf[256];
  int b = blockIdx.x, hh = blockIdx.y, n0 = blockIdx.z*64;
  int t = threadIdx.x, w = t>>6, lane = t&63;
  const float* kpg = kv + (((size_t)b*2 + 0)*384 + hh*48)*PK_;
  const float* vpg = kv + (((size_t)b*2 + 1)*384 + hh*48)*PK_;
  for(int idx=t; idx<48*64; idx+=256){
    int dd = idx>>6, kk = idx&63;
    kp[kk*52+dd] = kpg[idx];
    vp[dd*68+kk] = vpg[idx];
  }
  for(int idx=t; idx<64*48; idx+=256){
    int r = idx/48, dd = idx - r*48;
    float v = bf2f(qkv[((size_t)(b*N_+n0+r))*J3_ + hh*48 + dd]);
    qs[r*52+dd] = v * scale[b*C_ + hh*48 + dd];
  }
  __syncthreads();
  #pragma unroll 1
  for(int i=0;i<16;i++){
    int r = w*16 + i;
    const f4* qr  = reinterpret_cast<const f4*>(qs + r*52);
    const f4* kpr = reinterpret_cast<const f4*>(kp + lane*52);
    float lg = 0.f;
    #pragma unroll
    for(int d4=0; d4<12; d4++){
      f4 a = qr[d4], bb = kpr[d4];
      lg += a[0]*bb[0] + a[1]*bb[1] + a[2]*bb[2] + a[3]*bb[3];
    }
    float mx = lg;
    #pragma unroll
    for(int mk=32; mk>=1; mk>>=1) mx = fmaxf(mx, __shfl_xor(mx, mk, 64));
    float e = __expf(lg - mx);
    float sm = e;
    #pragma unroll
    for(int mk=32; mk>=1; mk>>=1) sm += __shfl_xor(sm, mk, 64);
    pbuf[w*64+lane] = e / sm;
    if(lane < 48){
      const f4* pr  = reinterpret_cast<const f4*>(pbuf + w*64);
      const f4* vpr = reinterpret_cast<const f4*>(vp + lane*68);
      float acc = 0.f;
      #pragma unroll
      for(int k4=0;k4<16;k4++){
        f4 pv = pr[k4], vv = vpr[k4];
        acc += pv[0]*vv[0] + pv[1]*vv[1] + pv[2]*vv[2] + pv[3]*vv[3];
      }
      qs[r*52+lane] = acc;   // overwrite consumed q row
    }
  }
  __syncthreads();
  for(int idx=t; idx<48*64; idx+=256){
    int dd = idx>>6, r = idx&63;
    xsa[(size_t)b*CN_ + (size_t)(dd*8+hh)*N_ + n0 + r] = qs[r*52+dd];
  }
}

// ---- 7) out[b][c][n] = xsa[b][n*384+c] (faithful reshape), tiled transpose ----
__global__ __launch_bounds__(256) void k_tout(const float* __restrict__ xsa, float* __restrict__ out){
  __shared__ float tile[32][33];
  int b = blockIdx.z, n0 = blockIdx.x*32, c0 = blockIdx.y*32;
  int t = threadIdx.x, tr = t>>5, tc = t&31;
  #pragma unroll
  for(int i=0;i<4;i++)
    tile[tr+i*8][tc] = xsa[(size_t)b*CN_ + (size_t)(n0+tr+i*8)*C_ + c0+tc];
  __syncthreads();
  #pragma unroll
  for(int i=0;i<4;i++)
    out[(size_t)b*CN_ + (size_t)(c0+tr+i*8)*N_ + n0+tc] = tile[tc][tr+i*8];
}

extern "C" void kernel_launch(void* const* d_in, const int* in_sizes, int n_in,
                              void* d_out, int out_size, void* d_ws, size_t ws_size,
                              hipStream_t stream){
  const float* x     = (const float*)d_in[0];
  const float* Wq    = (const float*)d_in[1];
  const float* EF    = (const float*)d_in[2];
  const float* temp2 = (const float*)d_in[3];
  float* out = (float*)d_out;
  char* ws = (char*)d_ws;
  // ws layout (bytes), total 77,174,784
  unsigned short* xb  = (unsigned short*)(ws);             // 12,582,912
  unsigned short* Wt  = (unsigned short*)(ws + 12582912);  //    884,736
  unsigned short* qkv = (unsigned short*)(ws + 13467648);  // 37,748,736
  float* scale        = (float*)(ws + 51216384);           //      6,144
  float* kv           = (float*)(ws + 51222528);           //    786,432
  float* xsa          = (float*)(ws + 52008960);           // 25,165,824

  k_tx  <<<dim3(128,12,4), 256, 0, stream>>>(x, xb);
  k_pw  <<<dim3(36,12),    256, 0, stream>>>(Wq, Wt);
  k_gemm<<<dim3(128,9),    256, 0, stream>>>(xb, Wt, qkv);
  k_norm<<<dim3(4,6),      256, 0, stream>>>(qkv, temp2, scale);
  k_kvproj<<<dim3(4,2,6),  256, 0, stream>>>(qkv, EF, kv);
  k_attn<<<dim3(4,8,64),   256, 0, stream>>>(qkv, scale, kv, xsa);
  k_tout<<<dim3(128,12,4), 256, 0, stream>>>(xsa, out);
}

// Round 2
// 435.817 us; speedup vs baseline: 2.5894x; 2.5894x over previous
//
#include <hip/hip_runtime.h>

#define B_ 4
#define C_ 384
#define N_ 4096
#define NH_ 8
#define D_ 48
#define PK_ 64
#define J3_ 1152
#define CN_ (C_*N_)
#define NCHUNK 16
#define CHN (N_/NCHUNK)          // 256 n per chunk
#define KVELEMS (B_*2*C_*PK_)    // 196608

using bf16x8 = __attribute__((ext_vector_type(8))) __bf16;
using f32x4  = __attribute__((ext_vector_type(4))) float;
using f4     = __attribute__((ext_vector_type(4))) float;

__device__ __forceinline__ float bf2f(unsigned short u){ return __uint_as_float(((unsigned)u)<<16); }
__device__ __forceinline__ unsigned short f2bf(float f){
  unsigned x = __float_as_uint(f);
  x += 0x7fffu + ((x>>16)&1u);
  return (unsigned short)(x>>16);
}

// ---- 1) x [B,C,N] f32 -> xb [B,N,C] bf16 (tiled transpose) ----
__global__ __launch_bounds__(256) void k_tx(const float* __restrict__ x, unsigned short* __restrict__ xb){
  __shared__ float tile[32][33];
  int b = blockIdx.z, n0 = blockIdx.x*32, c0 = blockIdx.y*32;
  int t = threadIdx.x, tr = t>>5, tc = t&31;
  #pragma unroll
  for(int i=0;i<4;i++)
    tile[tr+i*8][tc] = x[(size_t)b*CN_ + (size_t)(c0+tr+i*8)*N_ + n0+tc];
  __syncthreads();
  #pragma unroll
  for(int i=0;i<4;i++)
    xb[((size_t)b*N_ + n0+tr+i*8)*C_ + c0+tc] = f2bf(tile[tc][tr+i*8]);
}

// ---- 2) Wq [C,1536] f32 -> Wt [1152,384] bf16 (slices {0,1,3}, transposed) ----
__global__ __launch_bounds__(256) void k_pw(const float* __restrict__ Wq, unsigned short* __restrict__ Wt){
  __shared__ float tile[32][33];
  int j0 = blockIdx.x*32, c0 = blockIdx.y*32;
  int t = threadIdx.x, tr = t>>5, tc = t&31;
  #pragma unroll
  for(int i=0;i<4;i++){
    int c = c0+tr+i*8;
    int jp = j0+tc;
    int s = jp/384; int srcs = (s==2)?3:s;
    tile[tr+i*8][tc] = Wq[(size_t)c*1536 + srcs*384 + (jp - s*384)];
  }
  __syncthreads();
  #pragma unroll
  for(int i=0;i<4;i++){
    int j = j0+tr+i*8, c = c0+tc;
    Wt[(size_t)j*C_ + c] = f2bf(tile[tc][tr+i*8]);
  }
}

// ---- 3) qkv [16384,1152] bf16 = xb [16384,384] @ Wt^T, MFMA 16x16x32 ----
__global__ __launch_bounds__(256) void k_gemm(const unsigned short* __restrict__ A,
                                              const unsigned short* __restrict__ Bt,
                                              unsigned short* __restrict__ Cc){
  __shared__ alignas(16) unsigned short As[128*64];
  __shared__ alignas(16) unsigned short Bs[128*64];
  int t = threadIdx.x;
  int w = t>>6, l = t&63;
  int m0 = blockIdx.x*128, j0 = blockIdx.y*128;
  int lrow = l & 15;
  int rb = (w>>1)*64, cb = (w&1)*64;
  f32x4 acc[4][4] = {};
  for(int kt=0;kt<6;kt++){
    __syncthreads();
    int k0 = kt*64;
    #pragma unroll
    for(int i=0;i<4;i++){
      int r = (t>>3) + i*32;
      int slot = (t&7) ^ (r&7);          // inverse-swizzled global source (rule #21)
      const unsigned short* ga = A  + (size_t)(m0+r)*384 + k0 + slot*8;
      __builtin_amdgcn_global_load_lds((const __attribute__((address_space(1))) void*)ga,
                                       (__attribute__((address_space(3))) void*)(As + i*2048 + t*8), 16, 0, 0);
      const unsigned short* gb = Bt + (size_t)(j0+r)*384 + k0 + slot*8;
      __builtin_amdgcn_global_load_lds((const __attribute__((address_space(1))) void*)gb,
                                       (__attribute__((address_space(3))) void*)(Bs + i*2048 + t*8), 16, 0, 0);
    }
    __syncthreads();
    #pragma unroll
    for(int ks=0;ks<2;ks++){
      int kb0 = (ks*32 + ((l>>4)<<3))*2;  // byte offset of this lane's k-octet
      bf16x8 af[4], bf[4];
      #pragma unroll
      for(int mi=0;mi<4;mi++){
        int r = rb + mi*16 + lrow;
        int off = (r*128 + kb0) ^ ((r&7)<<4);   // swizzled ds_read
        af[mi] = *reinterpret_cast<const bf16x8*>((const char*)As + off);
      }
      #pragma unroll
      for(int ni=0;ni<4;ni++){
        int r = cb + ni*16 + lrow;
        int off = (r*128 + kb0) ^ ((r&7)<<4);
        bf[ni] = *reinterpret_cast<const bf16x8*>((const char*)Bs + off);
      }
      #pragma unroll
      for(int mi=0;mi<4;mi++)
        #pragma unroll
        for(int ni=0;ni<4;ni++)
          acc[mi][ni] = __builtin_amdgcn_mfma_f32_16x16x32_bf16(af[mi], bf[ni], acc[mi][ni], 0,0,0);
    }
  }
  int rq = (l>>4)<<2;
  #pragma unroll
  for(int mi=0;mi<4;mi++){
    #pragma unroll
    for(int ni=0;ni<4;ni++){
      int row = m0 + rb + mi*16 + rq;     // D: row=(l>>4)*4+q, col=l&15 (m89 verified)
      int col = j0 + cb + ni*16 + lrow;
      #pragma unroll
      for(int q=0;q<4;q++)
        Cc[(size_t)(row+q)*J3_ + col] = f2bf(acc[mi][ni][q]);
    }
  }
}

// ---- 4) scale[b][c'] = temp2[h] / max(||q_col||, 1e-12), norm over N ----
__global__ __launch_bounds__(256) void k_norm(const unsigned short* __restrict__ qkv,
                                              const float* __restrict__ temp2,
                                              float* __restrict__ scale){
  __shared__ float red[256];
  int b = blockIdx.x; int cc = blockIdx.y*64 + (threadIdx.x&63); int g = threadIdx.x>>6;
  float acc = 0.f;
  for(int n=g;n<N_;n+=4){
    float v = bf2f(qkv[((size_t)(b*N_+n))*J3_ + cc]);   // slice 0 = q
    acc += v*v;
  }
  red[threadIdx.x] = acc;
  __syncthreads();
  if(threadIdx.x < 64){
    float s = red[threadIdx.x] + red[threadIdx.x+64] + red[threadIdx.x+128] + red[threadIdx.x+192];
    int c = blockIdx.y*64 + threadIdx.x;
    float nrm = fmaxf(sqrtf(s), 1e-12f);
    scale[b*C_ + c] = temp2[c/48] / nrm;
  }
}

// ---- 5a) split-K partial: part[chunk][bs][c'][kk] = sum_{n in chunk} qkv * EF ----
__global__ __launch_bounds__(256) void k_kvproj_p1(const unsigned short* __restrict__ qkv,
                                                   const float* __restrict__ EF,
                                                   float* __restrict__ part){
  int bs = blockIdx.x;            // b*2+s
  int b = bs>>1, s = bs&1;
  int chunk = blockIdx.y;
  int w = threadIdx.x>>6, lane = threadIdx.x&63;
  int c0 = (blockIdx.z*4 + w)*16;
  float acc[16];
  #pragma unroll
  for(int j=0;j<16;j++) acc[j]=0.f;
  const unsigned short* base = qkv + (size_t)b*N_*J3_ + (s+1)*384 + c0;
  int n0 = chunk*CHN;
  #pragma unroll 1
  for(int nn=0;nn<CHN;nn+=2){
    int n = n0+nn;
    const uint4* p0 = reinterpret_cast<const uint4*>(base + (size_t)n*J3_);
    const uint4* p1 = reinterpret_cast<const uint4*>(base + (size_t)(n+1)*J3_);
    uint4 a0 = p0[0], a1 = p0[1];
    uint4 b0 = p1[0], b1 = p1[1];
    float ef0 = EF[(size_t)n*PK_ + lane];
    float ef1 = EF[(size_t)(n+1)*PK_ + lane];
    float va[16], vb[16];
    va[0]=__uint_as_float(a0.x<<16);  va[1]=__uint_as_float(a0.x&0xffff0000u);
    va[2]=__uint_as_float(a0.y<<16);  va[3]=__uint_as_float(a0.y&0xffff0000u);
    va[4]=__uint_as_float(a0.z<<16);  va[5]=__uint_as_float(a0.z&0xffff0000u);
    va[6]=__uint_as_float(a0.w<<16);  va[7]=__uint_as_float(a0.w&0xffff0000u);
    va[8]=__uint_as_float(a1.x<<16);  va[9]=__uint_as_float(a1.x&0xffff0000u);
    va[10]=__uint_as_float(a1.y<<16); va[11]=__uint_as_float(a1.y&0xffff0000u);
    va[12]=__uint_as_float(a1.z<<16); va[13]=__uint_as_float(a1.z&0xffff0000u);
    va[14]=__uint_as_float(a1.w<<16); va[15]=__uint_as_float(a1.w&0xffff0000u);
    vb[0]=__uint_as_float(b0.x<<16);  vb[1]=__uint_as_float(b0.x&0xffff0000u);
    vb[2]=__uint_as_float(b0.y<<16);  vb[3]=__uint_as_float(b0.y&0xffff0000u);
    vb[4]=__uint_as_float(b0.z<<16);  vb[5]=__uint_as_float(b0.z&0xffff0000u);
    vb[6]=__uint_as_float(b0.w<<16);  vb[7]=__uint_as_float(b0.w&0xffff0000u);
    vb[8]=__uint_as_float(b1.x<<16);  vb[9]=__uint_as_float(b1.x&0xffff0000u);
    vb[10]=__uint_as_float(b1.y<<16); vb[11]=__uint_as_float(b1.y&0xffff0000u);
    vb[12]=__uint_as_float(b1.z<<16); vb[13]=__uint_as_float(b1.z&0xffff0000u);
    vb[14]=__uint_as_float(b1.w<<16); vb[15]=__uint_as_float(b1.w&0xffff0000u);
    #pragma unroll
    for(int j=0;j<16;j++) acc[j] = fmaf(va[j], ef0, acc[j]);
    #pragma unroll
    for(int j=0;j<16;j++) acc[j] = fmaf(vb[j], ef1, acc[j]);
  }
  float* dst = part + (size_t)chunk*KVELEMS + ((size_t)(bs*C_) + c0)*PK_ + lane;
  #pragma unroll
  for(int j=0;j<16;j++) dst[(size_t)j*PK_] = acc[j];
}

// ---- 5b) deterministic reduce of NCHUNK partials ----
__global__ __launch_bounds__(256) void k_kvred(const float* __restrict__ part, float* __restrict__ kv){
  int e = blockIdx.x*256 + threadIdx.x;
  float s = 0.f;
  #pragma unroll
  for(int ch=0; ch<NCHUNK; ch++) s += part[(size_t)ch*KVELEMS + e];
  kv[e] = s;
}

// ---- 6) fused attention: logits -> softmax(64) -> PV; writes xsa[b][(dd*8+hh)*N + n] ----
__global__ __launch_bounds__(256) void k_attn(const unsigned short* __restrict__ qkv,
                                              const float* __restrict__ scale,
                                              const float* __restrict__ kv,
                                              float* __restrict__ xsa){
  __shared__ float qs[64*52];   // q*scale, later reused as output tile
  __shared__ float kp[64*52];   // [kk][dd] padded
  __shared__ float vp[48*68];   // [dd][kk] padded
  __shared__ float pbuf[256];
  int b = blockIdx.x, hh = blockIdx.y, n0 = blockIdx.z*64;
  int t = threadIdx.x, w = t>>6, lane = t&63;
  const float* kpg = kv + (((size_t)b*2 + 0)*384 + hh*48)*PK_;
  const float* vpg = kv + (((size_t)b*2 + 1)*384 + hh*48)*PK_;
  for(int idx=t; idx<48*64; idx+=256){
    int dd = idx>>6, kk = idx&63;
    kp[kk*52+dd] = kpg[idx];
    vp[dd*68+kk] = vpg[idx];
  }
  for(int idx=t; idx<64*48; idx+=256){
    int r = idx/48, dd = idx - r*48;
    float v = bf2f(qkv[((size_t)(b*N_+n0+r))*J3_ + hh*48 + dd]);
    qs[r*52+dd] = v * scale[b*C_ + hh*48 + dd];
  }
  __syncthreads();
  #pragma unroll 1
  for(int i=0;i<16;i++){
    int r = w*16 + i;
    const f4* qr  = reinterpret_cast<const f4*>(qs + r*52);
    const f4* kpr = reinterpret_cast<const f4*>(kp + lane*52);
    float lg = 0.f;
    #pragma unroll
    for(int d4=0; d4<12; d4++){
      f4 a = qr[d4], bb = kpr[d4];
      lg += a[0]*bb[0] + a[1]*bb[1] + a[2]*bb[2] + a[3]*bb[3];
    }
    float mx = lg;
    #pragma unroll
    for(int mk=32; mk>=1; mk>>=1) mx = fmaxf(mx, __shfl_xor(mx, mk, 64));
    float e = __expf(lg - mx);
    float sm = e;
    #pragma unroll
    for(int mk=32; mk>=1; mk>>=1) sm += __shfl_xor(sm, mk, 64);
    pbuf[w*64+lane] = e / sm;
    if(lane < 48){
      const f4* pr  = reinterpret_cast<const f4*>(pbuf + w*64);
      const f4* vpr = reinterpret_cast<const f4*>(vp + lane*68);
      float acc = 0.f;
      #pragma unroll
      for(int k4=0;k4<16;k4++){
        f4 pv = pr[k4], vv = vpr[k4];
        acc += pv[0]*vv[0] + pv[1]*vv[1] + pv[2]*vv[2] + pv[3]*vv[3];
      }
      qs[r*52+lane] = acc;   // overwrite consumed q row
    }
  }
  __syncthreads();
  for(int idx=t; idx<48*64; idx+=256){
    int dd = idx>>6, r = idx&63;
    xsa[(size_t)b*CN_ + (size_t)(dd*8+hh)*N_ + n0 + r] = qs[r*52+dd];
  }
}

// ---- 7) out[b][c][n] = xsa[b][n*384+c] (faithful reshape), tiled transpose ----
__global__ __launch_bounds__(256) void k_tout(const float* __restrict__ xsa, float* __restrict__ out){
  __shared__ float tile[32][33];
  int b = blockIdx.z, n0 = blockIdx.x*32, c0 = blockIdx.y*32;
  int t = threadIdx.x, tr = t>>5, tc = t&31;
  #pragma unroll
  for(int i=0;i<4;i++)
    tile[tr+i*8][tc] = xsa[(size_t)b*CN_ + (size_t)(n0+tr+i*8)*C_ + c0+tc];
  __syncthreads();
  #pragma unroll
  for(int i=0;i<4;i++)
    out[(size_t)b*CN_ + (size_t)(c0+tr+i*8)*N_ + n0+tc] = tile[tc][tr+i*8];
}

extern "C" void kernel_launch(void* const* d_in, const int* in_sizes, int n_in,
                              void* d_out, int out_size, void* d_ws, size_t ws_size,
                              hipStream_t stream){
  const float* x     = (const float*)d_in[0];
  const float* Wq    = (const float*)d_in[1];
  const float* EF    = (const float*)d_in[2];
  const float* temp2 = (const float*)d_in[3];
  float* out = (float*)d_out;
  char* ws = (char*)d_ws;
  // ws layout (bytes), total 77,174,784
  unsigned short* xb  = (unsigned short*)(ws);             // 12,582,912 (reused as kv partials after gemm)
  unsigned short* Wt  = (unsigned short*)(ws + 12582912);  //    884,736
  unsigned short* qkv = (unsigned short*)(ws + 13467648);  // 37,748,736
  float* scale        = (float*)(ws + 51216384);           //      6,144
  float* kv           = (float*)(ws + 51222528);           //    786,432
  float* xsa          = (float*)(ws + 52008960);           // 25,165,824
  float* kvpart       = (float*)(ws);                      // NCHUNK*196608*4 = 12,582,912 (aliases xb; xb dead after k_gemm)

  k_tx  <<<dim3(128,12,4), 256, 0, stream>>>(x, xb);
  k_pw  <<<dim3(36,12),    256, 0, stream>>>(Wq, Wt);
  k_gemm<<<dim3(128,9),    256, 0, stream>>>(xb, Wt, qkv);
  k_norm<<<dim3(4,6),      256, 0, stream>>>(qkv, temp2, scale);
  k_kvproj_p1<<<dim3(8,NCHUNK,6), 256, 0, stream>>>(qkv, EF, kvpart);
  k_kvred<<<dim3(KVELEMS/256), 256, 0, stream>>>(kvpart, kv);
  k_attn<<<dim3(4,8,64),   256, 0, stream>>>(qkv, scale, kv, xsa);
  k_tout<<<dim3(128,12,4), 256, 0, stream>>>(xsa, out);
}

// Round 4
// 196.340 us; speedup vs baseline: 5.7478x; 2.2197x over previous
//
#include <hip/hip_runtime.h>

#define B_ 4
#define C_ 384
#define N_ 4096
#define NH_ 8
#define D_ 48
#define PK_ 64
#define J3_ 1152
#define CN_ (C_*N_)
#define NCHUNK 16
#define CHN (N_/NCHUNK)          // 256 n per chunk
#define KVELEMS (B_*2*C_*PK_)    // 196608
#define NORMCH 32                // n-chunks for q-norm

using bf16x8 = __attribute__((ext_vector_type(8))) __bf16;
using f32x4  = __attribute__((ext_vector_type(4))) float;
using f4     = __attribute__((ext_vector_type(4))) float;

__device__ __forceinline__ float bf2f(unsigned short u){ return __uint_as_float(((unsigned)u)<<16); }
__device__ __forceinline__ unsigned short f2bf(float f){
  unsigned x = __float_as_uint(f);
  x += 0x7fffu + ((x>>16)&1u);
  return (unsigned short)(x>>16);
}

// ---- 1) x [B,C,N] f32 -> xb [B,N,C] bf16 (tiled transpose) ----
__global__ __launch_bounds__(256) void k_tx(const float* __restrict__ x, unsigned short* __restrict__ xb){
  __shared__ float tile[32][33];
  int b = blockIdx.z, n0 = blockIdx.x*32, c0 = blockIdx.y*32;
  int t = threadIdx.x, tr = t>>5, tc = t&31;
  #pragma unroll
  for(int i=0;i<4;i++)
    tile[tr+i*8][tc] = x[(size_t)b*CN_ + (size_t)(c0+tr+i*8)*N_ + n0+tc];
  __syncthreads();
  #pragma unroll
  for(int i=0;i<4;i++)
    xb[((size_t)b*N_ + n0+tr+i*8)*C_ + c0+tc] = f2bf(tile[tc][tr+i*8]);
}

// ---- 2) Wq [C,1536] f32 -> Wt [1152,384] bf16 (slices {0,1,3}, transposed) ----
__global__ __launch_bounds__(256) void k_pw(const float* __restrict__ Wq, unsigned short* __restrict__ Wt){
  __shared__ float tile[32][33];
  int j0 = blockIdx.x*32, c0 = blockIdx.y*32;
  int t = threadIdx.x, tr = t>>5, tc = t&31;
  #pragma unroll
  for(int i=0;i<4;i++){
    int c = c0+tr+i*8;
    int jp = j0+tc;
    int s = jp/384; int srcs = (s==2)?3:s;
    tile[tr+i*8][tc] = Wq[(size_t)c*1536 + srcs*384 + (jp - s*384)];
  }
  __syncthreads();
  #pragma unroll
  for(int i=0;i<4;i++){
    int j = j0+tr+i*8, c = c0+tc;
    Wt[(size_t)j*C_ + c] = f2bf(tile[tc][tr+i*8]);
  }
}

// ---- 3) qkv [16384,1152] bf16 = xb [16384,384] @ Wt^T, MFMA 16x16x32 ----
__global__ __launch_bounds__(256) void k_gemm(const unsigned short* __restrict__ A,
                                              const unsigned short* __restrict__ Bt,
                                              unsigned short* __restrict__ Cc){
  __shared__ alignas(16) unsigned short As[128*64];
  __shared__ alignas(16) unsigned short Bs[128*64];
  int t = threadIdx.x;
  int w = t>>6, l = t&63;
  int m0 = blockIdx.x*128, j0 = blockIdx.y*128;
  int lrow = l & 15;
  int rb = (w>>1)*64, cb = (w&1)*64;
  f32x4 acc[4][4] = {};
  for(int kt=0;kt<6;kt++){
    __syncthreads();
    int k0 = kt*64;
    #pragma unroll
    for(int i=0;i<4;i++){
      int r = (t>>3) + i*32;
      int slot = (t&7) ^ (r&7);          // inverse-swizzled global source (rule #21)
      const unsigned short* ga = A  + (size_t)(m0+r)*384 + k0 + slot*8;
      __builtin_amdgcn_global_load_lds((const __attribute__((address_space(1))) void*)ga,
                                       (__attribute__((address_space(3))) void*)(As + i*2048 + t*8), 16, 0, 0);
      const unsigned short* gb = Bt + (size_t)(j0+r)*384 + k0 + slot*8;
      __builtin_amdgcn_global_load_lds((const __attribute__((address_space(1))) void*)gb,
                                       (__attribute__((address_space(3))) void*)(Bs + i*2048 + t*8), 16, 0, 0);
    }
    __syncthreads();
    #pragma unroll
    for(int ks=0;ks<2;ks++){
      int kb0 = (ks*32 + ((l>>4)<<3))*2;  // byte offset of this lane's k-octet
      bf16x8 af[4], bf[4];
      #pragma unroll
      for(int mi=0;mi<4;mi++){
        int r = rb + mi*16 + lrow;
        int off = (r*128 + kb0) ^ ((r&7)<<4);   // swizzled ds_read
        af[mi] = *reinterpret_cast<const bf16x8*>((const char*)As + off);
      }
      #pragma unroll
      for(int ni=0;ni<4;ni++){
        int r = cb + ni*16 + lrow;
        int off = (r*128 + kb0) ^ ((r&7)<<4);
        bf[ni] = *reinterpret_cast<const bf16x8*>((const char*)Bs + off);
      }
      #pragma unroll
      for(int mi=0;mi<4;mi++)
        #pragma unroll
        for(int ni=0;ni<4;ni++)
          acc[mi][ni] = __builtin_amdgcn_mfma_f32_16x16x32_bf16(af[mi], bf[ni], acc[mi][ni], 0,0,0);
    }
  }
  int rq = (l>>4)<<2;
  #pragma unroll
  for(int mi=0;mi<4;mi++){
    #pragma unroll
    for(int ni=0;ni<4;ni++){
      int row = m0 + rb + mi*16 + rq;     // D: row=(l>>4)*4+q, col=l&15 (m89 verified)
      int col = j0 + cb + ni*16 + lrow;
      #pragma unroll
      for(int q=0;q<4;q++)
        Cc[(size_t)(row+q)*J3_ + col] = f2bf(acc[mi][ni][q]);
    }
  }
}

// ---- 4a) q-norm partials: part[b][chunk][c] = sum_{n in chunk} q^2 ----
// 384 threads: (rr = t/48 in 0..7 rows-in-flight, cg = t%48 col-group of 8).
// Per-thread partials are reduced across rr via LDS before the single
// exclusive global write (R3 bug: 8 threads raced on the same address).
__global__ __launch_bounds__(384) void k_norm_p1(const unsigned short* __restrict__ qkv,
                                                 float* __restrict__ part){
  __shared__ float red[8][384];
  int b = blockIdx.x, chunk = blockIdx.y;
  int t = threadIdx.x;
  int rr = t/48;          // row-within-group 0..7
  int cg = t - rr*48;     // col-group 0..47
  int c0 = cg*8;
  float acc[8];
  #pragma unroll
  for(int j=0;j<8;j++) acc[j]=0.f;
  int n0 = chunk*(N_/NORMCH);
  #pragma unroll 2
  for(int it=0; it<16; it++){
    int n = n0 + it*8 + rr;
    const uint4* p = reinterpret_cast<const uint4*>(qkv + ((size_t)(b*N_+n))*J3_ + c0);
    uint4 u0 = p[0], u1 = p[1];
    float v[8];
    v[0]=__uint_as_float(u0.x<<16);  v[1]=__uint_as_float(u0.x&0xffff0000u);
    v[2]=__uint_as_float(u0.y<<16);  v[3]=__uint_as_float(u0.y&0xffff0000u);
    v[4]=__uint_as_float(u0.z<<16);  v[5]=__uint_as_float(u0.z&0xffff0000u);
    v[6]=__uint_as_float(u0.w<<16);  v[7]=__uint_as_float(u0.w&0xffff0000u);
    (void)u1;
    #pragma unroll
    for(int j=0;j<8;j++) acc[j] = fmaf(v[j], v[j], acc[j]);
  }
  #pragma unroll
  for(int j=0;j<8;j++) red[rr][c0+j] = acc[j];
  __syncthreads();
  // one exclusive writer per column c = t (t < 384)
  float s = 0.f;
  #pragma unroll
  for(int r=0;r<8;r++) s += red[r][t];
  part[((size_t)b*NORMCH + chunk)*384 + t] = s;
}

// ---- 4b) reduce partials -> scale[b][c] = temp2[h]/max(||q_col||,1e-12) ----
__global__ __launch_bounds__(256) void k_norm_p2(const float* __restrict__ part,
                                                 const float* __restrict__ temp2,
                                                 float* __restrict__ scale){
  int idx = blockIdx.x*256 + threadIdx.x;   // 0..1535
  int b = idx / 384, c = idx - b*384;
  float s = 0.f;
  #pragma unroll
  for(int ch=0; ch<NORMCH; ch++) s += part[((size_t)b*NORMCH + ch)*384 + c];
  scale[b*C_ + c] = temp2[c/48] / fmaxf(sqrtf(s), 1e-12f);
}

// ---- 5a) split-K partial: part[chunk][bs][c'][kk] = sum_{n in chunk} qkv * EF ----
__global__ __launch_bounds__(256) void k_kvproj_p1(const unsigned short* __restrict__ qkv,
                                                   const float* __restrict__ EF,
                                                   float* __restrict__ part){
  int bs = blockIdx.x;            // b*2+s
  int b = bs>>1, s = bs&1;
  int chunk = blockIdx.y;
  int w = threadIdx.x>>6, lane = threadIdx.x&63;
  int c0 = (blockIdx.z*4 + w)*16;
  float acc[16];
  #pragma unroll
  for(int j=0;j<16;j++) acc[j]=0.f;
  const unsigned short* base = qkv + (size_t)b*N_*J3_ + (s+1)*384 + c0;
  int n0 = chunk*CHN;
  #pragma unroll 1
  for(int nn=0;nn<CHN;nn+=2){
    int n = n0+nn;
    const uint4* p0 = reinterpret_cast<const uint4*>(base + (size_t)n*J3_);
    const uint4* p1 = reinterpret_cast<const uint4*>(base + (size_t)(n+1)*J3_);
    uint4 a0 = p0[0], a1 = p0[1];
    uint4 b0 = p1[0], b1 = p1[1];
    float ef0 = EF[(size_t)n*PK_ + lane];
    float ef1 = EF[(size_t)(n+1)*PK_ + lane];
    float va[16], vb[16];
    va[0]=__uint_as_float(a0.x<<16);  va[1]=__uint_as_float(a0.x&0xffff0000u);
    va[2]=__uint_as_float(a0.y<<16);  va[3]=__uint_as_float(a0.y&0xffff0000u);
    va[4]=__uint_as_float(a0.z<<16);  va[5]=__uint_as_float(a0.z&0xffff0000u);
    va[6]=__uint_as_float(a0.w<<16);  va[7]=__uint_as_float(a0.w&0xffff0000u);
    va[8]=__uint_as_float(a1.x<<16);  va[9]=__uint_as_float(a1.x&0xffff0000u);
    va[10]=__uint_as_float(a1.y<<16); va[11]=__uint_as_float(a1.y&0xffff0000u);
    va[12]=__uint_as_float(a1.z<<16); va[13]=__uint_as_float(a1.z&0xffff0000u);
    va[14]=__uint_as_float(a1.w<<16); va[15]=__uint_as_float(a1.w&0xffff0000u);
    vb[0]=__uint_as_float(b0.x<<16);  vb[1]=__uint_as_float(b0.x&0xffff0000u);
    vb[2]=__uint_as_float(b0.y<<16);  vb[3]=__uint_as_float(b0.y&0xffff0000u);
    vb[4]=__uint_as_float(b0.z<<16);  vb[5]=__uint_as_float(b0.z&0xffff0000u);
    vb[6]=__uint_as_float(b0.w<<16);  vb[7]=__uint_as_float(b0.w&0xffff0000u);
    vb[8]=__uint_as_float(b1.x<<16);  vb[9]=__uint_as_float(b1.x&0xffff0000u);
    vb[10]=__uint_as_float(b1.y<<16); vb[11]=__uint_as_float(b1.y&0xffff0000u);
    vb[12]=__uint_as_float(b1.z<<16); vb[13]=__uint_as_float(b1.z&0xffff0000u);
    vb[14]=__uint_as_float(b1.w<<16); vb[15]=__uint_as_float(b1.w&0xffff0000u);
    #pragma unroll
    for(int j=0;j<16;j++) acc[j] = fmaf(va[j], ef0, acc[j]);
    #pragma unroll
    for(int j=0;j<16;j++) acc[j] = fmaf(vb[j], ef1, acc[j]);
  }
  float* dst = part + (size_t)chunk*KVELEMS + ((size_t)(bs*C_) + c0)*PK_ + lane;
  #pragma unroll
  for(int j=0;j<16;j++) dst[(size_t)j*PK_] = acc[j];
}

// ---- 5b) deterministic reduce of NCHUNK partials ----
__global__ __launch_bounds__(256) void k_kvred(const float* __restrict__ part, float* __restrict__ kv){
  int e = blockIdx.x*256 + threadIdx.x;
  float s = 0.f;
  #pragma unroll
  for(int ch=0; ch<NCHUNK; ch++) s += part[(size_t)ch*KVELEMS + e];
  kv[e] = s;
}

// ---- 6) fused attention: logits -> softmax(64) -> PV; writes xsa[b][(dd*8+hh)*N + n] ----
__global__ __launch_bounds__(256) void k_attn(const unsigned short* __restrict__ qkv,
                                              const float* __restrict__ scale,
                                              const float* __restrict__ kv,
                                              float* __restrict__ xsa){
  __shared__ float qs[64*52];   // q*scale, later reused as output tile
  __shared__ float kp[64*52];   // [kk][dd] padded
  __shared__ float vp[48*68];   // [dd][kk] padded
  __shared__ float pbuf[256];
  int b = blockIdx.x, hh = blockIdx.y, n0 = blockIdx.z*64;
  int t = threadIdx.x, w = t>>6, lane = t&63;
  const float* kpg = kv + (((size_t)b*2 + 0)*384 + hh*48)*PK_;
  const float* vpg = kv + (((size_t)b*2 + 1)*384 + hh*48)*PK_;
  for(int idx=t; idx<48*64; idx+=256){
    int dd = idx>>6, kk = idx&63;
    kp[kk*52+dd] = kpg[idx];
    vp[dd*68+kk] = vpg[idx];
  }
  for(int idx=t; idx<64*48; idx+=256){
    int r = idx/48, dd = idx - r*48;
    float v = bf2f(qkv[((size_t)(b*N_+n0+r))*J3_ + hh*48 + dd]);
    qs[r*52+dd] = v * scale[b*C_ + hh*48 + dd];
  }
  __syncthreads();
  #pragma unroll 1
  for(int i=0;i<16;i++){
    int r = w*16 + i;
    const f4* qr  = reinterpret_cast<const f4*>(qs + r*52);
    const f4* kpr = reinterpret_cast<const f4*>(kp + lane*52);
    float lg = 0.f;
    #pragma unroll
    for(int d4=0; d4<12; d4++){
      f4 a = qr[d4], bb = kpr[d4];
      lg += a[0]*bb[0] + a[1]*bb[1] + a[2]*bb[2] + a[3]*bb[3];
    }
    float mx = lg;
    #pragma unroll
    for(int mk=32; mk>=1; mk>>=1) mx = fmaxf(mx, __shfl_xor(mx, mk, 64));
    float e = __expf(lg - mx);
    float sm = e;
    #pragma unroll
    for(int mk=32; mk>=1; mk>>=1) sm += __shfl_xor(sm, mk, 64);
    pbuf[w*64+lane] = e / sm;
    if(lane < 48){
      const f4* pr  = reinterpret_cast<const f4*>(pbuf + w*64);
      const f4* vpr = reinterpret_cast<const f4*>(vp + lane*68);
      float acc = 0.f;
      #pragma unroll
      for(int k4=0;k4<16;k4++){
        f4 pv = pr[k4], vv = vpr[k4];
        acc += pv[0]*vv[0] + pv[1]*vv[1] + pv[2]*vv[2] + pv[3]*vv[3];
      }
      qs[r*52+lane] = acc;   // overwrite consumed q row
    }
  }
  __syncthreads();
  for(int idx=t; idx<48*64; idx+=256){
    int dd = idx>>6, r = idx&63;
    xsa[(size_t)b*CN_ + (size_t)(dd*8+hh)*N_ + n0 + r] = qs[r*52+dd];
  }
}

// ---- 7) out[b][c][n] = xsa[b][n*384+c] (faithful reshape), tiled transpose ----
__global__ __launch_bounds__(256) void k_tout(const float* __restrict__ xsa, float* __restrict__ out){
  __shared__ float tile[32][33];
  int b = blockIdx.z, n0 = blockIdx.x*32, c0 = blockIdx.y*32;
  int t = threadIdx.x, tr = t>>5, tc = t&31;
  #pragma unroll
  for(int i=0;i<4;i++)
    tile[tr+i*8][tc] = xsa[(size_t)b*CN_ + (size_t)(n0+tr+i*8)*C_ + c0+tc];
  __syncthreads();
  #pragma unroll
  for(int i=0;i<4;i++)
    out[(size_t)b*CN_ + (size_t)(c0+tr+i*8)*N_ + n0+tc] = tile[tc][tr+i*8];
}

extern "C" void kernel_launch(void* const* d_in, const int* in_sizes, int n_in,
                              void* d_out, int out_size, void* d_ws, size_t ws_size,
                              hipStream_t stream){
  const float* x     = (const float*)d_in[0];
  const float* Wq    = (const float*)d_in[1];
  const float* EF    = (const float*)d_in[2];
  const float* temp2 = (const float*)d_in[3];
  float* out = (float*)d_out;
  char* ws = (char*)d_ws;
  // ws layout (bytes), total 77,174,784
  unsigned short* xb  = (unsigned short*)(ws);             // 12,582,912 (reused as kv partials after gemm)
  unsigned short* Wt  = (unsigned short*)(ws + 12582912);  //    884,736 (reused as norm partials after gemm)
  unsigned short* qkv = (unsigned short*)(ws + 13467648);  // 37,748,736
  float* scale        = (float*)(ws + 51216384);           //      6,144
  float* kv           = (float*)(ws + 51222528);           //    786,432
  float* xsa          = (float*)(ws + 52008960);           // 25,165,824
  float* kvpart       = (float*)(ws);                      // 16*196608*4 = 12,582,912 (aliases xb)
  float* normpart     = (float*)(ws + 12582912);           // 4*32*384*4 = 196,608 (aliases Wt)

  k_tx  <<<dim3(128,12,4), 256, 0, stream>>>(x, xb);
  k_pw  <<<dim3(36,12),    256, 0, stream>>>(Wq, Wt);
  k_gemm<<<dim3(128,9),    256, 0, stream>>>(xb, Wt, qkv);
  k_norm_p1<<<dim3(4,NORMCH), 384, 0, stream>>>(qkv, normpart);
  k_norm_p2<<<dim3(6),        256, 0, stream>>>(normpart, temp2, scale);
  k_kvproj_p1<<<dim3(8,NCHUNK,6), 256, 0, stream>>>(qkv, EF, kvpart);
  k_kvred<<<dim3(KVELEMS/256), 256, 0, stream>>>(kvpart, kv);
  k_attn<<<dim3(4,8,64),   256, 0, stream>>>(qkv, scale, kv, xsa);
  k_tout<<<dim3(128,12,4), 256, 0, stream>>>(xsa, out);
}